// Round 6
// baseline (143.767 us; speedup 1.0000x reference)
//
#include <hip/hip_runtime.h>

typedef __attribute__((ext_vector_type(2))) _Float16 h2;
typedef __attribute__((ext_vector_type(2))) __fp16 p2;   // cvt_pkrtz return type
typedef __attribute__((ext_vector_type(8))) _Float16 f16x8;
typedef __attribute__((ext_vector_type(4))) float fv4;
typedef __attribute__((ext_vector_type(4))) int iv4;

#define K_IN 4096
#define N_OUT 4096

// ---------------------------------------------------------------------------
// Kernel 1: xa[b][r] = sum_i x[b][i] * lora_a[r][i]
// ---------------------------------------------------------------------------
__global__ __launch_bounds__(256) void xa_kernel(const float* __restrict__ x,
                                                 const float* __restrict__ la,
                                                 float* __restrict__ xa) {
    int tid = blockIdx.x * 256 + threadIdx.x;
    int ks = tid & 15;
    int p = tid >> 4;           // 0..16383 = b*16 + r
    int b = p >> 4, r = p & 15;
    const fv4* xp = (const fv4*)(x + (size_t)b * K_IN + ks * 256);
    const fv4* ap = (const fv4*)(la + (size_t)r * K_IN + ks * 256);
    float acc = 0.f;
#pragma unroll 8
    for (int i = 0; i < 64; ++i) {
        fv4 xv = xp[i], av = ap[i];
        acc += xv.x * av.x + xv.y * av.y + xv.z * av.z + xv.w * av.w;
    }
    acc += __shfl_xor(acc, 1);
    acc += __shfl_xor(acc, 2);
    acc += __shfl_xor(acc, 4);
    acc += __shfl_xor(acc, 8);
    if (ks == 0) xa[p] = acc;
}

struct RegSet {
    fv4 Ar[8];
    iv4 Bqa, Bqb;
    float Bsc;
};

// ---------------------------------------------------------------------------
// Kernel 2: fused dequant GEMM + rank-16 LoRA.
// 512 blocks x 256 thr (4 waves). BM=128, BN=64, BK=64, 64 K-steps.
// Wave grid (wm,kg)=2x2: wave tile 64x64 over one k32 half of each K-step.
// Distance-2 register pipeline: loads for tile t+2 issued at iter t; LDS
// store of tile t+1 waits a COUNTED vmcnt (loads 1 full iter old). Hot-loop
// barrier is raw s_barrier + lgkmcnt(0) only -- in-flight global loads are
// never drained (the __syncthreads vmcnt(0) drain was the R5 bottleneck).
// LDS 80KB -> 2 blocks/CU:
//   A f16 dbuf [128 rows][128B] @0/16384   (granule XOR swizzle g^(row&7))
//   B f16 dbuf [64 cols][128B] @32768/40960 (g^(col&7))
//   partial-acc dump @49152 + wm*16384
// ---------------------------------------------------------------------------
__global__ __launch_bounds__(256, 2) void qlora_gemm(
        const float* __restrict__ x, const int* __restrict__ qw,
        const float* __restrict__ sc, const float* __restrict__ lb,
        const float* __restrict__ alphap, const float* __restrict__ xa,
        float* __restrict__ out)
{
    __shared__ __align__(16) char lds[81920];

    // XCD q = bid&7 owns one by (A panel shared within XCD).
    int bid = blockIdx.x;
    int by = bid & 7, bx = bid >> 3;   // 8 x 64 tiles
    int bm0 = by << 7, bn0 = bx << 6;

    int t = threadIdx.x;
    int lane = t & 63;
    int wid = t >> 6;                  // 0..3
    int kg = wid & 1, wm = wid >> 1;
    int rl = lane & 15, hq = lane >> 4;
    int r7 = rl & 7;

    // ---- A staging: inst i covers row = i*32 + (t>>3), k-granule t&7 ----
    int arow = t >> 3;                 // 0..31 (+i*32)
    int ag = t & 7;
    const float* agp = x + (size_t)(bm0 + arow) * K_IN + ag * 8;

    // ---- B staging: thread -> (colB = t>>2, q4 = t&3) ----
    int colB = t >> 2, q4 = t & 3;
    const int* qwp = qw + ((size_t)(bn0 + colB) * 256 + q4) * 8;
    const float* scp = sc + (size_t)(bn0 + colB) * 256 + q4;

    auto load_set = [&](RegSet& rs, int ts) {
#pragma unroll
        for (int i = 0; i < 4; ++i) {
            const float* p = agp + (size_t)i * 32 * K_IN + ts * 64;
            rs.Ar[2 * i] = *(const fv4*)(p);
            rs.Ar[2 * i + 1] = *(const fv4*)(p + 4);
        }
        rs.Bqa = *(const iv4*)(qwp + (size_t)ts * 32);
        rs.Bqb = *(const iv4*)(qwp + (size_t)ts * 32 + 4);
        rs.Bsc = scp[(size_t)ts * 4];
    };

    auto store_set = [&](const RegSet& rs, int buf) {
        char* As = lds + buf * 16384;
        char* Bs = lds + 32768 + buf * 8192;
#pragma unroll
        for (int i = 0; i < 4; ++i) {
            int row = i * 32 + arow;
            union { p2 h[4]; iv4 v; } u;
            u.h[0] = __builtin_amdgcn_cvt_pkrtz(rs.Ar[2 * i].x, rs.Ar[2 * i].y);
            u.h[1] = __builtin_amdgcn_cvt_pkrtz(rs.Ar[2 * i].z, rs.Ar[2 * i].w);
            u.h[2] = __builtin_amdgcn_cvt_pkrtz(rs.Ar[2 * i + 1].x, rs.Ar[2 * i + 1].y);
            u.h[3] = __builtin_amdgcn_cvt_pkrtz(rs.Ar[2 * i + 1].z, rs.Ar[2 * i + 1].w);
            *(iv4*)(As + row * 128 + ((ag ^ (row & 7)) << 4)) = u.v;
        }
        float s = rs.Bsc;
        _Float16 c0h = (_Float16)(s * (2.0f / 15.0f));
        _Float16 c1h = (_Float16)(-s);
        h2 c0 = {c0h, c0h}, c1 = {c1h, c1h};
        h2 m1024 = {(_Float16)-1024.f, (_Float16)-1024.f};
        union { h2 h[4]; iv4 v; } o0, o1;
        int vals[8] = {rs.Bqa.x, rs.Bqa.y, rs.Bqa.z, rs.Bqa.w,
                       rs.Bqb.x, rs.Bqb.y, rs.Bqb.z, rs.Bqb.w};
#pragma unroll
        for (int e = 0; e < 8; ++e) {
            unsigned wv = (unsigned)vals[e];
            unsigned qb = (wv & 15u) | ((wv & 0xF0u) << 12) | 0x64006400u;
            h2 qh;
            __builtin_memcpy(&qh, &qb, 4);
            h2 r = (qh + m1024) * c0 + c1;
            if (e < 4) o0.h[e] = r; else o1.h[e - 4] = r;
        }
        int c7 = colB & 7;
        *(iv4*)(Bs + colB * 128 + (((2 * q4) ^ c7) << 4)) = o0.v;
        *(iv4*)(Bs + colB * 128 + (((2 * q4 + 1) ^ c7) << 4)) = o1.v;
    };

    fv4 acc[4][4];
#pragma unroll
    for (int m = 0; m < 4; ++m)
#pragma unroll
        for (int n = 0; n < 4; ++n)
            acc[m][n] = fv4{0.f, 0.f, 0.f, 0.f};

    auto COMPUTE = [&](int buf, int kgg) {
        const char* As = lds + buf * 16384;
        const char* Bs = lds + 32768 + buf * 8192;
        f16x8 a[4], b[4];
        int gk = kgg * 4 + hq;
        int gs = (gk ^ r7) << 4;
#pragma unroll
        for (int m = 0; m < 4; ++m) {
            int row = wm * 64 + m * 16 + rl;
            a[m] = *(const f16x8*)(As + row * 128 + gs);
        }
#pragma unroll
        for (int n = 0; n < 4; ++n) {
            int col = n * 16 + rl;
            b[n] = *(const f16x8*)(Bs + col * 128 + gs);
        }
        __builtin_amdgcn_s_setprio(1);
#pragma unroll
        for (int m = 0; m < 4; ++m)
#pragma unroll
            for (int n = 0; n < 4; ++n)
                acc[m][n] = __builtin_amdgcn_mfma_f32_16x16x32_f16(
                    a[m], b[n], acc[m][n], 0, 0, 0);
        __builtin_amdgcn_s_setprio(0);
    };

#define SOFT_BARRIER() do { \
        asm volatile("s_waitcnt lgkmcnt(0)" ::: "memory"); \
        __builtin_amdgcn_s_barrier(); \
        __builtin_amdgcn_sched_barrier(0); \
    } while (0)

    RegSet s0, s1;
    // ---- prologue: tiles 0,1 in flight; tile0 -> buf0 ----
    load_set(s0, 0);
    load_set(s1, 1);
    store_set(s0, 0);         // counted wait: s1's 11 loads stay in flight
    SOFT_BARRIER();

    // ---- main loop: 2 tiles per iteration ----
#pragma unroll 1
    for (int ts = 0; ts < 64; ts += 2) {
        if (ts + 2 < 64) load_set(s0, ts + 2);
        COMPUTE(0, kg);                     // buf0 = tile ts
        store_set(s1, 1);                   // tile ts+1 -> buf1 (loads 1 iter old)
        SOFT_BARRIER();

        if (ts + 3 < 64) load_set(s1, ts + 3);
        COMPUTE(1, kg);                     // buf1 = tile ts+1
        if (ts + 2 < 64) store_set(s0, 0);  // tile ts+2 -> buf0
        SOFT_BARRIER();
    }

    // ---- LoRA rank-16 extra K-step into buf0 (k 0..15 data, 16..31 zeros) ----
    {
#pragma unroll
        for (int i = 0; i < 4; ++i) {
            int row = i * 32 + arow;
            union { p2 h[4]; iv4 v; } u;
            if (ag < 2) {
                const float* xp2 = xa + (size_t)(bm0 + row) * 16 + ag * 8;
                fv4 v0 = *(const fv4*)(xp2);
                fv4 v1 = *(const fv4*)(xp2 + 4);
                u.h[0] = __builtin_amdgcn_cvt_pkrtz(v0.x, v0.y);
                u.h[1] = __builtin_amdgcn_cvt_pkrtz(v0.z, v0.w);
                u.h[2] = __builtin_amdgcn_cvt_pkrtz(v1.x, v1.y);
                u.h[3] = __builtin_amdgcn_cvt_pkrtz(v1.z, v1.w);
            } else {
                u.v = iv4{0, 0, 0, 0};
            }
            *(iv4*)(lds + row * 128 + ((ag ^ (row & 7)) << 4)) = u.v;
        }
        float al = alphap[0];
        union { p2 h[4]; iv4 v; } ob0, ob1;
        if (q4 == 0) {
            const float* wp = lb + (size_t)(bn0 + colB) * 16;
#pragma unroll
            for (int e = 0; e < 4; ++e) {
                ob0.h[e] = __builtin_amdgcn_cvt_pkrtz(al * wp[2 * e], al * wp[2 * e + 1]);
                ob1.h[e] = __builtin_amdgcn_cvt_pkrtz(al * wp[8 + 2 * e], al * wp[9 + 2 * e]);
            }
        } else {
            ob0.v = iv4{0, 0, 0, 0};
            ob1.v = iv4{0, 0, 0, 0};
        }
        int c7 = colB & 7;
        *(iv4*)(lds + 32768 + colB * 128 + (((2 * q4) ^ c7) << 4)) = ob0.v;
        *(iv4*)(lds + 32768 + colB * 128 + (((2 * q4 + 1) ^ c7) << 4)) = ob1.v;
    }
    __syncthreads();

    if (kg == 0) {
        COMPUTE(0, 0);
    } else {
        // kg==1: dump partials for the kg==0 partner (same wm).
        char* dmp = lds + 49152 + wm * 16384;
#pragma unroll
        for (int m = 0; m < 4; ++m)
#pragma unroll
            for (int n = 0; n < 4; ++n)
                *(fv4*)(dmp + (m * 4 + n) * 1024 + lane * 16) = acc[m][n];
    }
    __syncthreads();

    if (kg == 0) {
        const char* dmp = lds + 49152 + wm * 16384;
#pragma unroll
        for (int m = 0; m < 4; ++m) {
            int row0 = bm0 + wm * 64 + m * 16 + hq * 4;
#pragma unroll
            for (int n = 0; n < 4; ++n) {
                fv4 p = *(const fv4*)(dmp + (m * 4 + n) * 1024 + lane * 16);
                fv4 v = acc[m][n];
                v.x += p.x; v.y += p.y; v.z += p.z; v.w += p.w;
                int col = bn0 + n * 16 + rl;
#pragma unroll
                for (int r = 0; r < 4; ++r)
                    out[(size_t)(row0 + r) * N_OUT + col] = v[r];
            }
        }
    }
#undef SOFT_BARRIER
}

extern "C" void kernel_launch(void* const* d_in, const int* in_sizes, int n_in,
                              void* d_out, int out_size, void* d_ws, size_t ws_size,
                              hipStream_t stream) {
    const float* x  = (const float*)d_in[0];
    const int*   qw = (const int*)d_in[1];
    const float* sc = (const float*)d_in[2];
    const float* la = (const float*)d_in[3];
    const float* lb = (const float*)d_in[4];
    const float* al = (const float*)d_in[5];
    float* out = (float*)d_out;
    float* xa  = (float*)d_ws;   // 1024*16 fp32 = 64 KB scratch

    xa_kernel<<<1024, 256, 0, stream>>>(x, la, xa);
    qlora_gemm<<<512, 256, 0, stream>>>(x, qw, sc, lb, al, xa, out);
}

// Round 7
// 139.918 us; speedup vs baseline: 1.0275x; 1.0275x over previous
//
#include <hip/hip_runtime.h>

typedef __attribute__((ext_vector_type(2))) _Float16 h2;
typedef __attribute__((ext_vector_type(2))) __fp16 p2;   // cvt_pkrtz return type
typedef __attribute__((ext_vector_type(8))) _Float16 f16x8;
typedef __attribute__((ext_vector_type(4))) float fv4;
typedef __attribute__((ext_vector_type(4))) int iv4;
typedef unsigned int u32;

#define K_IN 4096
#define N_OUT 4096
#define KE 4160   /* extended K: 4096 data + 16 lora + 48 zero pad */

// ---------------------------------------------------------------------------
// xa[b][r] = sum_i x[b][i] * lora_a[r][i]
// ---------------------------------------------------------------------------
__global__ __launch_bounds__(256) void xa_kernel(const float* __restrict__ x,
                                                 const float* __restrict__ la,
                                                 float* __restrict__ xa) {
    int tid = blockIdx.x * 256 + threadIdx.x;
    int ks = tid & 15;
    int p = tid >> 4;           // 0..16383 = b*16 + r
    int b = p >> 4, r = p & 15;
    const fv4* xp = (const fv4*)(x + (size_t)b * K_IN + ks * 256);
    const fv4* ap = (const fv4*)(la + (size_t)r * K_IN + ks * 256);
    float acc = 0.f;
#pragma unroll 8
    for (int i = 0; i < 64; ++i) {
        fv4 xv = xp[i], av = ap[i];
        acc += xv.x * av.x + xv.y * av.y + xv.z * av.z + xv.w * av.w;
    }
    acc += __shfl_xor(acc, 1);
    acc += __shfl_xor(acc, 2);
    acc += __shfl_xor(acc, 4);
    acc += __shfl_xor(acc, 8);
    if (ks == 0) xa[p] = acc;
}

// ---------------------------------------------------------------------------
// W dequant: one thread per group (16 weights) -> Wh[o][i0..i0+16] f16.
// grp = o*256 + i/16 ; interleave (lo,hi) nibbles; w = q*(2s/15) - s.
// ---------------------------------------------------------------------------
__global__ __launch_bounds__(256) void w_dequant(const int* __restrict__ qw,
                                                 const float* __restrict__ sc,
                                                 _Float16* __restrict__ Wh) {
    int grp = blockIdx.x * 256 + threadIdx.x;      // 0..1048575
    int o = grp >> 8;
    int i0 = (grp & 255) << 4;
    const int* qp = qw + (size_t)grp * 8;
    iv4 q0 = *(const iv4*)qp;
    iv4 q1 = *(const iv4*)(qp + 4);
    float s = sc[grp];
    _Float16 c0h = (_Float16)(s * (2.0f / 15.0f));
    _Float16 c1h = (_Float16)(-s);
    h2 c0 = {c0h, c0h}, c1 = {c1h, c1h};
    h2 m1024 = {(_Float16)-1024.f, (_Float16)-1024.f};
    union { h2 h[4]; iv4 v; } o0, o1;
    int vals[8] = {q0.x, q0.y, q0.z, q0.w, q1.x, q1.y, q1.z, q1.w};
#pragma unroll
    for (int e = 0; e < 8; ++e) {
        unsigned wv = (unsigned)vals[e];
        unsigned qb = (wv & 15u) | ((wv & 0xF0u) << 12) | 0x64006400u;
        h2 qh;
        __builtin_memcpy(&qh, &qb, 4);
        h2 r = (qh + m1024) * c0 + c1;
        if (e < 4) o0.h[e] = r; else o1.h[e - 4] = r;
    }
    _Float16* wp = Wh + (size_t)o * KE + i0;
    *(iv4*)(wp) = o0.v;
    *(iv4*)(wp + 8) = o1.v;
}

// ---------------------------------------------------------------------------
// W pad: cols 4096..4111 = alpha*lora_b[o][:], 4112..4159 = 0.
// One thread per 8-f16 chunk: 4096 rows x 8 chunks = 32768 threads.
// ---------------------------------------------------------------------------
__global__ __launch_bounds__(256) void w_pad(const float* __restrict__ lb,
                                             const float* __restrict__ alphap,
                                             _Float16* __restrict__ Wh) {
    int c = blockIdx.x * 256 + threadIdx.x;        // 0..32767
    int o = c >> 3, j = c & 7;
    union { p2 h[4]; iv4 v; } u;
    u.v = iv4{0, 0, 0, 0};
    if (j < 2) {
        float al = alphap[0];
        const float* wp = lb + (size_t)o * 16 + j * 8;
#pragma unroll
        for (int e = 0; e < 4; ++e)
            u.h[e] = __builtin_amdgcn_cvt_pkrtz(al * wp[2 * e], al * wp[2 * e + 1]);
    }
    *(iv4*)(Wh + (size_t)o * KE + 4096 + j * 8) = u.v;
}

// ---------------------------------------------------------------------------
// xh build: xh[b][0..4095] = f16(x), [4096..4111] = f16(xa[b][:]), rest 0.
// One thread per 8-f16 chunk: 1024 x 520 chunks = 532480 threads.
// ---------------------------------------------------------------------------
__global__ __launch_bounds__(256) void x_build(const float* __restrict__ x,
                                               const float* __restrict__ xa,
                                               _Float16* __restrict__ xh) {
    int c = blockIdx.x * 256 + threadIdx.x;        // 0..532479
    int b = (int)((unsigned)c / 520u);
    int col8 = c - b * 520;
    union { p2 h[4]; iv4 v; } u;
    if (col8 < 512) {
        const float* p = x + (size_t)b * K_IN + col8 * 8;
        fv4 v0 = *(const fv4*)(p);
        fv4 v1 = *(const fv4*)(p + 4);
        u.h[0] = __builtin_amdgcn_cvt_pkrtz(v0.x, v0.y);
        u.h[1] = __builtin_amdgcn_cvt_pkrtz(v0.z, v0.w);
        u.h[2] = __builtin_amdgcn_cvt_pkrtz(v1.x, v1.y);
        u.h[3] = __builtin_amdgcn_cvt_pkrtz(v1.z, v1.w);
    } else if (col8 < 514) {
        const float* p = xa + (size_t)b * 16 + (col8 - 512) * 8;
        fv4 v0 = *(const fv4*)(p);
        fv4 v1 = *(const fv4*)(p + 4);
        u.h[0] = __builtin_amdgcn_cvt_pkrtz(v0.x, v0.y);
        u.h[1] = __builtin_amdgcn_cvt_pkrtz(v0.z, v0.w);
        u.h[2] = __builtin_amdgcn_cvt_pkrtz(v1.x, v1.y);
        u.h[3] = __builtin_amdgcn_cvt_pkrtz(v1.z, v1.w);
    } else {
        u.v = iv4{0, 0, 0, 0};
    }
    *(iv4*)(xh + (size_t)b * KE + col8 * 8) = u.v;
}

// ---------------------------------------------------------------------------
// Pass-2 GEMM: out[1024][4096] = xh[1024][KE] @ Wh[4096][KE]^T, f32 accum.
// 512 blocks x 256 thr (4 waves 2x2). BM=128, BN=64, BK=64, 65 K-steps.
// Both tiles staged via global_load_lds width=16 (no reg round-trip, no VALU).
// LDS 48KB (A dbuf 2x16KB @0, B dbuf 2x8KB @32768) -> 2 blocks/CU.
// Soft barrier: vmcnt(0) drain (loads had full compute phase) + raw s_barrier.
// XCD-chunked: bid&7 = by -> each XCD owns one 1MB A-panel (L2-resident).
// ---------------------------------------------------------------------------
__global__ __launch_bounds__(256, 2) void qlora_gemm2(
        const _Float16* __restrict__ xh, const _Float16* __restrict__ Wh,
        float* __restrict__ out)
{
    __shared__ __align__(16) char lds[49152];

    int bid = blockIdx.x;
    int by = bid & 7, bx = bid >> 3;    // 8 x 64 tiles
    int bm0 = by << 7, bn0 = bx << 6;

    int t = threadIdx.x;
    int lane = t & 63;
    int wid = t >> 6;                   // 0..3
    int wm = wid >> 1, wn = wid & 1;
    int rl = lane & 15, hq = lane >> 4;

    // per-lane gload sources (dest linear [row][128B])
    int lr = lane >> 3, lg = lane & 7;
    const char* asrc[4];
    const char* bsrc[2];
#pragma unroll
    for (int i = 0; i < 4; ++i) {
        int row = wid * 32 + i * 8 + lr;
        asrc[i] = (const char*)(xh + (size_t)(bm0 + row) * KE) + lg * 16;
    }
#pragma unroll
    for (int j = 0; j < 2; ++j) {
        int col = wid * 16 + j * 8 + lr;
        bsrc[j] = (const char*)(Wh + (size_t)(bn0 + col) * KE) + lg * 16;
    }

    auto GLOAD = [&](int ts, int buf) {
        char* Ad = lds + buf * 16384 + wid * 4096;
        char* Bd = lds + 32768 + buf * 8192 + wid * 2048;
#pragma unroll
        for (int i = 0; i < 4; ++i)
            __builtin_amdgcn_global_load_lds(
                (const __attribute__((address_space(1))) u32*)(asrc[i] + (size_t)ts * 128),
                (__attribute__((address_space(3))) u32*)(Ad + i * 1024), 16, 0, 0);
#pragma unroll
        for (int j = 0; j < 2; ++j)
            __builtin_amdgcn_global_load_lds(
                (const __attribute__((address_space(1))) u32*)(bsrc[j] + (size_t)ts * 128),
                (__attribute__((address_space(3))) u32*)(Bd + j * 1024), 16, 0, 0);
    };

    fv4 acc[4][2];
#pragma unroll
    for (int m = 0; m < 4; ++m)
#pragma unroll
        for (int n = 0; n < 2; ++n)
            acc[m][n] = fv4{0.f, 0.f, 0.f, 0.f};

    auto COMPUTE = [&](int buf) {
        const char* As = lds + buf * 16384;
        const char* Bs = lds + 32768 + buf * 8192;
#pragma unroll
        for (int ks = 0; ks < 2; ++ks) {
            f16x8 a[4], b[2];
            int go = (ks * 4 + hq) << 4;
#pragma unroll
            for (int m = 0; m < 4; ++m)
                a[m] = *(const f16x8*)(As + (wm * 64 + m * 16 + rl) * 128 + go);
#pragma unroll
            for (int n = 0; n < 2; ++n)
                b[n] = *(const f16x8*)(Bs + (wn * 32 + n * 16 + rl) * 128 + go);
            __builtin_amdgcn_s_setprio(1);
#pragma unroll
            for (int m = 0; m < 4; ++m)
#pragma unroll
                for (int n = 0; n < 2; ++n)
                    acc[m][n] = __builtin_amdgcn_mfma_f32_16x16x32_f16(
                        a[m], b[n], acc[m][n], 0, 0, 0);
            __builtin_amdgcn_s_setprio(0);
        }
    };

    GLOAD(0, 0);
    asm volatile("s_waitcnt vmcnt(0)" ::: "memory");
    __builtin_amdgcn_s_barrier();
    __builtin_amdgcn_sched_barrier(0);

#pragma unroll 1
    for (int ts = 0; ts < 65; ++ts) {
        int buf = ts & 1;
        if (ts < 64) GLOAD(ts + 1, buf ^ 1);   // loads fly under COMPUTE
        COMPUTE(buf);
        asm volatile("s_waitcnt vmcnt(0)" ::: "memory");
        __builtin_amdgcn_s_barrier();
        __builtin_amdgcn_sched_barrier(0);
    }

#pragma unroll
    for (int m = 0; m < 4; ++m) {
        int row0 = bm0 + wm * 64 + m * 16 + hq * 4;
#pragma unroll
        for (int n = 0; n < 2; ++n) {
            int col = bn0 + wn * 32 + n * 16 + rl;
#pragma unroll
            for (int r = 0; r < 4; ++r)
                out[(size_t)(row0 + r) * N_OUT + col] = acc[m][n][r];
        }
    }
}

// ===========================================================================
// Fallback (R6 fused path) for small ws_size.
// ===========================================================================
struct RegSet {
    fv4 Ar[8];
    iv4 Bqa, Bqb;
    float Bsc;
};

__global__ __launch_bounds__(256, 2) void qlora_gemm(
        const float* __restrict__ x, const int* __restrict__ qw,
        const float* __restrict__ sc, const float* __restrict__ lb,
        const float* __restrict__ alphap, const float* __restrict__ xa,
        float* __restrict__ out)
{
    __shared__ __align__(16) char lds[81920];

    int bid = blockIdx.x;
    int by = bid & 7, bx = bid >> 3;
    int bm0 = by << 7, bn0 = bx << 6;

    int t = threadIdx.x;
    int lane = t & 63;
    int wid = t >> 6;
    int kg = wid & 1, wm = wid >> 1;
    int rl = lane & 15, hq = lane >> 4;
    int r7 = rl & 7;

    int arow = t >> 3;
    int ag = t & 7;
    const float* agp = x + (size_t)(bm0 + arow) * K_IN + ag * 8;

    int colB = t >> 2, q4 = t & 3;
    const int* qwp = qw + ((size_t)(bn0 + colB) * 256 + q4) * 8;
    const float* scp = sc + (size_t)(bn0 + colB) * 256 + q4;

    auto load_set = [&](RegSet& rs, int ts) {
#pragma unroll
        for (int i = 0; i < 4; ++i) {
            const float* p = agp + (size_t)i * 32 * K_IN + ts * 64;
            rs.Ar[2 * i] = *(const fv4*)(p);
            rs.Ar[2 * i + 1] = *(const fv4*)(p + 4);
        }
        rs.Bqa = *(const iv4*)(qwp + (size_t)ts * 32);
        rs.Bqb = *(const iv4*)(qwp + (size_t)ts * 32 + 4);
        rs.Bsc = scp[(size_t)ts * 4];
    };

    auto store_set = [&](const RegSet& rs, int buf) {
        char* As = lds + buf * 16384;
        char* Bs = lds + 32768 + buf * 8192;
#pragma unroll
        for (int i = 0; i < 4; ++i) {
            int row = i * 32 + arow;
            union { p2 h[4]; iv4 v; } u;
            u.h[0] = __builtin_amdgcn_cvt_pkrtz(rs.Ar[2 * i].x, rs.Ar[2 * i].y);
            u.h[1] = __builtin_amdgcn_cvt_pkrtz(rs.Ar[2 * i].z, rs.Ar[2 * i].w);
            u.h[2] = __builtin_amdgcn_cvt_pkrtz(rs.Ar[2 * i + 1].x, rs.Ar[2 * i + 1].y);
            u.h[3] = __builtin_amdgcn_cvt_pkrtz(rs.Ar[2 * i + 1].z, rs.Ar[2 * i + 1].w);
            *(iv4*)(As + row * 128 + ((ag ^ (row & 7)) << 4)) = u.v;
        }
        float s = rs.Bsc;
        _Float16 c0h = (_Float16)(s * (2.0f / 15.0f));
        _Float16 c1h = (_Float16)(-s);
        h2 c0 = {c0h, c0h}, c1 = {c1h, c1h};
        h2 m1024 = {(_Float16)-1024.f, (_Float16)-1024.f};
        union { h2 h[4]; iv4 v; } o0, o1;
        int vals[8] = {rs.Bqa.x, rs.Bqa.y, rs.Bqa.z, rs.Bqa.w,
                       rs.Bqb.x, rs.Bqb.y, rs.Bqb.z, rs.Bqb.w};
#pragma unroll
        for (int e = 0; e < 8; ++e) {
            unsigned wv = (unsigned)vals[e];
            unsigned qb = (wv & 15u) | ((wv & 0xF0u) << 12) | 0x64006400u;
            h2 qh;
            __builtin_memcpy(&qh, &qb, 4);
            h2 r = (qh + m1024) * c0 + c1;
            if (e < 4) o0.h[e] = r; else o1.h[e - 4] = r;
        }
        int c7 = colB & 7;
        *(iv4*)(Bs + colB * 128 + (((2 * q4) ^ c7) << 4)) = o0.v;
        *(iv4*)(Bs + colB * 128 + (((2 * q4 + 1) ^ c7) << 4)) = o1.v;
    };

    fv4 acc[4][4];
#pragma unroll
    for (int m = 0; m < 4; ++m)
#pragma unroll
        for (int n = 0; n < 4; ++n)
            acc[m][n] = fv4{0.f, 0.f, 0.f, 0.f};

    auto COMPUTE = [&](int buf, int kgg) {
        const char* As = lds + buf * 16384;
        const char* Bs = lds + 32768 + buf * 8192;
        f16x8 a[4], b[4];
        int gk = kgg * 4 + hq;
        int gs = (gk ^ r7) << 4;
#pragma unroll
        for (int m = 0; m < 4; ++m) {
            int row = wm * 64 + m * 16 + rl;
            a[m] = *(const f16x8*)(As + row * 128 + gs);
        }
#pragma unroll
        for (int n = 0; n < 4; ++n) {
            int col = n * 16 + rl;
            b[n] = *(const f16x8*)(Bs + col * 128 + gs);
        }
        __builtin_amdgcn_s_setprio(1);
#pragma unroll
        for (int m = 0; m < 4; ++m)
#pragma unroll
            for (int n = 0; n < 4; ++n)
                acc[m][n] = __builtin_amdgcn_mfma_f32_16x16x32_f16(
                    a[m], b[n], acc[m][n], 0, 0, 0);
        __builtin_amdgcn_s_setprio(0);
    };

#define SOFT_BARRIER() do { \
        asm volatile("s_waitcnt lgkmcnt(0)" ::: "memory"); \
        __builtin_amdgcn_s_barrier(); \
        __builtin_amdgcn_sched_barrier(0); \
    } while (0)

    RegSet s0, s1;
    load_set(s0, 0);
    load_set(s1, 1);
    store_set(s0, 0);
    SOFT_BARRIER();

#pragma unroll 1
    for (int ts = 0; ts < 64; ts += 2) {
        if (ts + 2 < 64) load_set(s0, ts + 2);
        COMPUTE(0, kg);
        store_set(s1, 1);
        SOFT_BARRIER();

        if (ts + 3 < 64) load_set(s1, ts + 3);
        COMPUTE(1, kg);
        if (ts + 2 < 64) store_set(s0, 0);
        SOFT_BARRIER();
    }

    {
#pragma unroll
        for (int i = 0; i < 4; ++i) {
            int row = i * 32 + arow;
            union { p2 h[4]; iv4 v; } u;
            if (ag < 2) {
                const float* xp2 = xa + (size_t)(bm0 + row) * 16 + ag * 8;
                fv4 v0 = *(const fv4*)(xp2);
                fv4 v1 = *(const fv4*)(xp2 + 4);
                u.h[0] = __builtin_amdgcn_cvt_pkrtz(v0.x, v0.y);
                u.h[1] = __builtin_amdgcn_cvt_pkrtz(v0.z, v0.w);
                u.h[2] = __builtin_amdgcn_cvt_pkrtz(v1.x, v1.y);
                u.h[3] = __builtin_amdgcn_cvt_pkrtz(v1.z, v1.w);
            } else {
                u.v = iv4{0, 0, 0, 0};
            }
            *(iv4*)(lds + row * 128 + ((ag ^ (row & 7)) << 4)) = u.v;
        }
        float al = alphap[0];
        union { p2 h[4]; iv4 v; } ob0, ob1;
        if (q4 == 0) {
            const float* wp = lb + (size_t)(bn0 + colB) * 16;
#pragma unroll
            for (int e = 0; e < 4; ++e) {
                ob0.h[e] = __builtin_amdgcn_cvt_pkrtz(al * wp[2 * e], al * wp[2 * e + 1]);
                ob1.h[e] = __builtin_amdgcn_cvt_pkrtz(al * wp[8 + 2 * e], al * wp[9 + 2 * e]);
            }
        } else {
            ob0.v = iv4{0, 0, 0, 0};
            ob1.v = iv4{0, 0, 0, 0};
        }
        int c7 = colB & 7;
        *(iv4*)(lds + 32768 + colB * 128 + (((2 * q4) ^ c7) << 4)) = ob0.v;
        *(iv4*)(lds + 32768 + colB * 128 + (((2 * q4 + 1) ^ c7) << 4)) = ob1.v;
    }
    __syncthreads();

    if (kg == 0) {
        COMPUTE(0, 0);
    } else {
        char* dmp = lds + 49152 + wm * 16384;
#pragma unroll
        for (int m = 0; m < 4; ++m)
#pragma unroll
            for (int n = 0; n < 4; ++n)
                *(fv4*)(dmp + (m * 4 + n) * 1024 + lane * 16) = acc[m][n];
    }
    __syncthreads();

    if (kg == 0) {
        const char* dmp = lds + 49152 + wm * 16384;
#pragma unroll
        for (int m = 0; m < 4; ++m) {
            int row0 = bm0 + wm * 64 + m * 16 + hq * 4;
#pragma unroll
            for (int n = 0; n < 4; ++n) {
                fv4 p = *(const fv4*)(dmp + (m * 4 + n) * 1024 + lane * 16);
                fv4 v = acc[m][n];
                v.x += p.x; v.y += p.y; v.z += p.z; v.w += p.w;
                int col = bn0 + n * 16 + rl;
#pragma unroll
                for (int r = 0; r < 4; ++r)
                    out[(size_t)(row0 + r) * N_OUT + col] = v[r];
            }
        }
    }
#undef SOFT_BARRIER
}

extern "C" void kernel_launch(void* const* d_in, const int* in_sizes, int n_in,
                              void* d_out, int out_size, void* d_ws, size_t ws_size,
                              hipStream_t stream) {
    const float* x  = (const float*)d_in[0];
    const int*   qw = (const int*)d_in[1];
    const float* sc = (const float*)d_in[2];
    const float* la = (const float*)d_in[3];
    const float* lb = (const float*)d_in[4];
    const float* al = (const float*)d_in[5];
    float* out = (float*)d_out;

    const size_t WH_BYTES = (size_t)N_OUT * KE * 2;   // 34,078,720
    const size_t XH_BYTES = (size_t)1024 * KE * 2;    //  8,519,680
    const size_t XA_BYTES = (size_t)1024 * 16 * 4;    //     65,536

    if (ws_size >= WH_BYTES + XH_BYTES + XA_BYTES) {
        _Float16* Wh = (_Float16*)d_ws;
        _Float16* xh = (_Float16*)((char*)d_ws + WH_BYTES);
        float*    xa = (float*)((char*)d_ws + WH_BYTES + XH_BYTES);

        xa_kernel<<<1024, 256, 0, stream>>>(x, la, xa);
        w_dequant<<<4096, 256, 0, stream>>>(qw, sc, Wh);
        w_pad<<<128, 256, 0, stream>>>(lb, al, Wh);
        x_build<<<2080, 256, 0, stream>>>(x, xa, xh);
        qlora_gemm2<<<512, 256, 0, stream>>>(xh, Wh, out);
    } else {
        float* xa = (float*)d_ws;
        xa_kernel<<<1024, 256, 0, stream>>>(x, la, xa);
        qlora_gemm<<<512, 256, 0, stream>>>(x, qw, sc, lb, al, xa, out);
    }
}

// Round 8
// 84.676 us; speedup vs baseline: 1.6979x; 1.6524x over previous
//
#include <hip/hip_runtime.h>

typedef __attribute__((ext_vector_type(2))) _Float16 h2;
typedef __attribute__((ext_vector_type(2))) __fp16 p2;   // cvt_pkrtz return type
typedef __attribute__((ext_vector_type(8))) _Float16 f16x8;
typedef __attribute__((ext_vector_type(4))) float fv4;
typedef __attribute__((ext_vector_type(4))) int iv4;
typedef unsigned int u32;

#define K_IN 4096
#define N_OUT 4096
#define KE 4160   /* extended K: 4096 data + 16 lora + 48 zero pad */

// ---------------------------------------------------------------------------
// xa[b][r] = sum_i x[b][i] * lora_a[r][i]
// One block per b-row. Threads read x and la COALESCED (lane-consecutive fv4);
// 16 accs per thread over the r-loop; butterfly + LDS cross-wave reduce.
// ---------------------------------------------------------------------------
__global__ __launch_bounds__(256) void xa_kernel(const float* __restrict__ x,
                                                 const float* __restrict__ la,
                                                 float* __restrict__ xa) {
    int b = blockIdx.x;
    int t = threadIdx.x;
    const fv4* xp = (const fv4*)(x + (size_t)b * K_IN);
    fv4 xv[4];
#pragma unroll
    for (int j = 0; j < 4; ++j) xv[j] = xp[t + j * 256];
    float acc[16];
#pragma unroll
    for (int r = 0; r < 16; ++r) {
        const fv4* ap = (const fv4*)(la + (size_t)r * K_IN);
        float s = 0.f;
#pragma unroll
        for (int j = 0; j < 4; ++j) {
            fv4 av = ap[t + j * 256];
            s = fmaf(xv[j].x, av.x, s);
            s = fmaf(xv[j].y, av.y, s);
            s = fmaf(xv[j].z, av.z, s);
            s = fmaf(xv[j].w, av.w, s);
        }
        acc[r] = s;
    }
#pragma unroll
    for (int r = 0; r < 16; ++r) {
#pragma unroll
        for (int off = 1; off < 64; off <<= 1)
            acc[r] += __shfl_xor(acc[r], off);
    }
    __shared__ float red[4][16];
    int lane = t & 63, w = t >> 6;
    if (lane < 16) red[w][lane] = acc[lane];
    __syncthreads();
    if (t < 16) xa[b * 16 + t] = red[0][t] + red[1][t] + red[2][t] + red[3][t];
}

// ---------------------------------------------------------------------------
// W dequant: one thread per group (16 weights) -> Wh[o][i0..i0+16] f16.
// ---------------------------------------------------------------------------
__global__ __launch_bounds__(256) void w_dequant(const int* __restrict__ qw,
                                                 const float* __restrict__ sc,
                                                 _Float16* __restrict__ Wh) {
    int grp = blockIdx.x * 256 + threadIdx.x;      // 0..1048575
    int o = grp >> 8;
    int i0 = (grp & 255) << 4;
    const int* qp = qw + (size_t)grp * 8;
    iv4 q0 = *(const iv4*)qp;
    iv4 q1 = *(const iv4*)(qp + 4);
    float s = sc[grp];
    _Float16 c0h = (_Float16)(s * (2.0f / 15.0f));
    _Float16 c1h = (_Float16)(-s);
    h2 c0 = {c0h, c0h}, c1 = {c1h, c1h};
    h2 m1024 = {(_Float16)-1024.f, (_Float16)-1024.f};
    union { h2 h[4]; iv4 v; } o0, o1;
    int vals[8] = {q0.x, q0.y, q0.z, q0.w, q1.x, q1.y, q1.z, q1.w};
#pragma unroll
    for (int e = 0; e < 8; ++e) {
        unsigned wv = (unsigned)vals[e];
        unsigned qb = (wv & 15u) | ((wv & 0xF0u) << 12) | 0x64006400u;
        h2 qh;
        __builtin_memcpy(&qh, &qb, 4);
        h2 r = (qh + m1024) * c0 + c1;
        if (e < 4) o0.h[e] = r; else o1.h[e - 4] = r;
    }
    _Float16* wp = Wh + (size_t)o * KE + i0;
    *(iv4*)(wp) = o0.v;
    *(iv4*)(wp + 8) = o1.v;
}

// ---------------------------------------------------------------------------
// W pad: cols 4096..4111 = alpha*lora_b[o][:], 4112..4159 = 0.
// ---------------------------------------------------------------------------
__global__ __launch_bounds__(256) void w_pad(const float* __restrict__ lb,
                                             const float* __restrict__ alphap,
                                             _Float16* __restrict__ Wh) {
    int c = blockIdx.x * 256 + threadIdx.x;        // 0..32767
    int o = c >> 3, j = c & 7;
    union { p2 h[4]; iv4 v; } u;
    u.v = iv4{0, 0, 0, 0};
    if (j < 2) {
        float al = alphap[0];
        const float* wp = lb + (size_t)o * 16 + j * 8;
#pragma unroll
        for (int e = 0; e < 4; ++e)
            u.h[e] = __builtin_amdgcn_cvt_pkrtz(al * wp[2 * e], al * wp[2 * e + 1]);
    }
    *(iv4*)(Wh + (size_t)o * KE + 4096 + j * 8) = u.v;
}

// ---------------------------------------------------------------------------
// xh build: xh[b][0..4095] = f16(x), [4096..4111] = f16(xa[b][:]), rest 0.
// ---------------------------------------------------------------------------
__global__ __launch_bounds__(256) void x_build(const float* __restrict__ x,
                                               const float* __restrict__ xa,
                                               _Float16* __restrict__ xh) {
    int c = blockIdx.x * 256 + threadIdx.x;        // 0..532479
    int b = (int)((unsigned)c / 520u);
    int col8 = c - b * 520;
    union { p2 h[4]; iv4 v; } u;
    if (col8 < 512) {
        const float* p = x + (size_t)b * K_IN + col8 * 8;
        fv4 v0 = *(const fv4*)(p);
        fv4 v1 = *(const fv4*)(p + 4);
        u.h[0] = __builtin_amdgcn_cvt_pkrtz(v0.x, v0.y);
        u.h[1] = __builtin_amdgcn_cvt_pkrtz(v0.z, v0.w);
        u.h[2] = __builtin_amdgcn_cvt_pkrtz(v1.x, v1.y);
        u.h[3] = __builtin_amdgcn_cvt_pkrtz(v1.z, v1.w);
    } else if (col8 < 514) {
        const float* p = xa + (size_t)b * 16 + (col8 - 512) * 8;
        fv4 v0 = *(const fv4*)(p);
        fv4 v1 = *(const fv4*)(p + 4);
        u.h[0] = __builtin_amdgcn_cvt_pkrtz(v0.x, v0.y);
        u.h[1] = __builtin_amdgcn_cvt_pkrtz(v0.z, v0.w);
        u.h[2] = __builtin_amdgcn_cvt_pkrtz(v1.x, v1.y);
        u.h[3] = __builtin_amdgcn_cvt_pkrtz(v1.z, v1.w);
    } else {
        u.v = iv4{0, 0, 0, 0};
    }
    *(iv4*)(xh + (size_t)b * KE + col8 * 8) = u.v;
}

// ---------------------------------------------------------------------------
// Pass-2 GEMM v2: out = xh[1024][KE] @ Wh[4096][KE]^T, f32 accum.
// 256 blocks x 512 thr (8 waves: wm,wn,kg = 2x2x2; wave tile 64x64 over one
// k32 half of each BK=64 step). 65 K-steps. 1 block/CU.
// LDS 96KB: A f16 3-buf [128][128B] @0 (+16K/buf), B 3-buf @49152.
// Swizzle: DMA dest linear, SOURCE granule pre-XOR (lg^row&7); ds_read XOR.
// Distance-2 DMA pipeline with counted vmcnt(4) -- never drains in-loop.
// ---------------------------------------------------------------------------
__global__ __launch_bounds__(512, 1) void qlora_gemm2(
        const _Float16* __restrict__ xh, const _Float16* __restrict__ Wh,
        float* __restrict__ out)
{
    __shared__ __align__(16) char lds[98304];

    int bid = blockIdx.x;
    int by = bid & 7, bx = bid >> 3;    // 8 x 32 tiles of 128x128
    int bm0 = by << 7, bn0 = bx << 7;

    int t = threadIdx.x;
    int lane = t & 63;
    int wid = t >> 6;                   // 0..7
    int kg = wid & 1, wn = (wid >> 1) & 1, wm = wid >> 2;
    int rl = lane & 15, hq = lane >> 4;

    // staging map: inst i in {0,1}: slot = t + i*512 -> row slot>>3, lg slot&7
    int srow = t >> 3;                  // 0..63 (+64 for inst 1)
    int slg = t & 7;
    int sg = slg ^ (srow & 7);          // pre-swizzled source granule
    const char* a0 = (const char*)(xh + (size_t)(bm0 + srow) * KE) + sg * 16;
    const char* a1 = (const char*)(xh + (size_t)(bm0 + srow + 64) * KE) + sg * 16;
    const char* b0 = (const char*)(Wh + (size_t)(bn0 + srow) * KE) + sg * 16;
    const char* b1 = (const char*)(Wh + (size_t)(bn0 + srow + 64) * KE) + sg * 16;

    auto GLOAD = [&](int ts, int buf) {
        char* Ad = lds + buf * 16384;
        char* Bd = lds + 49152 + buf * 16384;
        size_t off = (size_t)ts * 128;
        __builtin_amdgcn_global_load_lds(
            (const __attribute__((address_space(1))) u32*)(a0 + off),
            (__attribute__((address_space(3))) u32*)(Ad + t * 16), 16, 0, 0);
        __builtin_amdgcn_global_load_lds(
            (const __attribute__((address_space(1))) u32*)(a1 + off),
            (__attribute__((address_space(3))) u32*)(Ad + 8192 + t * 16), 16, 0, 0);
        __builtin_amdgcn_global_load_lds(
            (const __attribute__((address_space(1))) u32*)(b0 + off),
            (__attribute__((address_space(3))) u32*)(Bd + t * 16), 16, 0, 0);
        __builtin_amdgcn_global_load_lds(
            (const __attribute__((address_space(1))) u32*)(b1 + off),
            (__attribute__((address_space(3))) u32*)(Bd + 8192 + t * 16), 16, 0, 0);
    };

    fv4 acc[4][4];
#pragma unroll
    for (int m = 0; m < 4; ++m)
#pragma unroll
        for (int n = 0; n < 4; ++n)
            acc[m][n] = fv4{0.f, 0.f, 0.f, 0.f};

    auto COMPUTE = [&](int buf) {
        const char* As = lds + buf * 16384;
        const char* Bs = lds + 49152 + buf * 16384;
        f16x8 a[4], b[4];
        int gk = kg * 4 + hq;               // granule 0..7 (this wave's k half)
        int gs = (gk ^ (rl & 7)) << 4;
#pragma unroll
        for (int m = 0; m < 4; ++m)
            a[m] = *(const f16x8*)(As + (wm * 64 + m * 16 + rl) * 128 + gs);
#pragma unroll
        for (int n = 0; n < 4; ++n)
            b[n] = *(const f16x8*)(Bs + (wn * 64 + n * 16 + rl) * 128 + gs);
        __builtin_amdgcn_s_setprio(1);
#pragma unroll
        for (int m = 0; m < 4; ++m)
#pragma unroll
            for (int n = 0; n < 4; ++n)
                acc[m][n] = __builtin_amdgcn_mfma_f32_16x16x32_f16(
                    a[m], b[n], acc[m][n], 0, 0, 0);
        __builtin_amdgcn_s_setprio(0);
    };

    // ---- prologue: tiles 0,1 in flight; wait tile0 only (counted) ----
    GLOAD(0, 0);
    GLOAD(1, 1);
    asm volatile("s_waitcnt vmcnt(4)" ::: "memory");
    __builtin_amdgcn_s_barrier();
    __builtin_amdgcn_sched_barrier(0);

    // ---- main loop: dist-2 prefetch, counted vmcnt, raw barrier ----
#pragma unroll 1
    for (int ts = 0; ts < 65; ++ts) {
        if (ts + 2 < 65) GLOAD(ts + 2, (ts + 2) % 3);
        COMPUTE(ts % 3);
        if (ts + 2 < 65)
            asm volatile("s_waitcnt vmcnt(4)" ::: "memory");  // tile ts+1 landed
        else
            asm volatile("s_waitcnt vmcnt(0)" ::: "memory");
        __builtin_amdgcn_s_barrier();
        __builtin_amdgcn_sched_barrier(0);
    }

    // ---- kg-split reduction + store ----
    if (kg == 1) {
        char* dmp = lds + (wm * 2 + wn) * 16384;
#pragma unroll
        for (int m = 0; m < 4; ++m)
#pragma unroll
            for (int n = 0; n < 4; ++n)
                *(fv4*)(dmp + (m * 4 + n) * 1024 + lane * 16) = acc[m][n];
    }
    __syncthreads();
    if (kg == 0) {
        const char* dmp = lds + (wm * 2 + wn) * 16384;
#pragma unroll
        for (int m = 0; m < 4; ++m) {
            int row0 = bm0 + wm * 64 + m * 16 + hq * 4;
#pragma unroll
            for (int n = 0; n < 4; ++n) {
                fv4 p = *(const fv4*)(dmp + (m * 4 + n) * 1024 + lane * 16);
                fv4 v = acc[m][n];
                v.x += p.x; v.y += p.y; v.z += p.z; v.w += p.w;
                int col = bn0 + wn * 64 + n * 16 + rl;
#pragma unroll
                for (int r = 0; r < 4; ++r)
                    out[(size_t)(row0 + r) * N_OUT + col] = v[r];
            }
        }
    }
}

extern "C" void kernel_launch(void* const* d_in, const int* in_sizes, int n_in,
                              void* d_out, int out_size, void* d_ws, size_t ws_size,
                              hipStream_t stream) {
    const float* x  = (const float*)d_in[0];
    const int*   qw = (const int*)d_in[1];
    const float* sc = (const float*)d_in[2];
    const float* la = (const float*)d_in[3];
    const float* lb = (const float*)d_in[4];
    const float* al = (const float*)d_in[5];
    float* out = (float*)d_out;

    const size_t WH_BYTES = (size_t)N_OUT * KE * 2;   // 34,078,720
    const size_t XH_BYTES = (size_t)1024 * KE * 2;    //  8,519,680
    const size_t XA_BYTES = (size_t)1024 * 16 * 4;    //     65,536

    _Float16* Wh = (_Float16*)d_ws;
    _Float16* xh = (_Float16*)((char*)d_ws + WH_BYTES);
    float*    xa = (float*)((char*)d_ws + WH_BYTES + XH_BYTES);
    (void)ws_size; (void)n_in; (void)in_sizes; (void)out_size;
    (void)XA_BYTES;

    xa_kernel<<<1024, 256, 0, stream>>>(x, la, xa);
    w_dequant<<<4096, 256, 0, stream>>>(qw, sc, Wh);
    w_pad<<<128, 256, 0, stream>>>(lb, al, Wh);
    x_build<<<2080, 256, 0, stream>>>(x, xa, xh);
    qlora_gemm2<<<256, 512, 0, stream>>>(xh, Wh, out);
}

// Round 9
// 73.127 us; speedup vs baseline: 1.9660x; 1.1579x over previous
//
#include <hip/hip_runtime.h>

typedef __attribute__((ext_vector_type(2))) _Float16 h2;
typedef __attribute__((ext_vector_type(2))) __fp16 p2;   // cvt_pkrtz return type
typedef __attribute__((ext_vector_type(8))) _Float16 f16x8;
typedef __attribute__((ext_vector_type(4))) float fv4;
typedef __attribute__((ext_vector_type(4))) int iv4;
typedef __attribute__((ext_vector_type(2))) int iv2;
typedef unsigned int u32;

#define K_IN 4096
#define N_OUT 4096
#define KE 4160   /* 4096 data + 16 lora + 48 zero pad */

// ---------------------------------------------------------------------------
// P1: fused xa + xh build. One block per b-row.
// Threads read x coalesced; 16 r-dots; write f16 row + lora cols + zero pad.
// ---------------------------------------------------------------------------
__global__ __launch_bounds__(256) void x_prep(const float* __restrict__ x,
                                              const float* __restrict__ la,
                                              _Float16* __restrict__ xh) {
    int b = blockIdx.x;
    int t = threadIdx.x;
    const fv4* xp = (const fv4*)(x + (size_t)b * K_IN);
    _Float16* xr = xh + (size_t)b * KE;
    fv4 xv[4];
#pragma unroll
    for (int j = 0; j < 4; ++j) xv[j] = xp[t + j * 256];
    // write main f16 cols (coalesced 8B per thread per j)
#pragma unroll
    for (int j = 0; j < 4; ++j) {
        union { p2 h[2]; iv2 v; } u;
        u.h[0] = __builtin_amdgcn_cvt_pkrtz(xv[j].x, xv[j].y);
        u.h[1] = __builtin_amdgcn_cvt_pkrtz(xv[j].z, xv[j].w);
        *(iv2*)(xr + (size_t)(t + j * 256) * 4) = u.v;
    }
    // 16 dots with lora_a rows (la is 256KB -> L2-resident)
    float acc[16];
#pragma unroll
    for (int r = 0; r < 16; ++r) {
        const fv4* ap = (const fv4*)(la + (size_t)r * K_IN);
        float s = 0.f;
#pragma unroll
        for (int j = 0; j < 4; ++j) {
            fv4 av = ap[t + j * 256];
            s = fmaf(xv[j].x, av.x, s);
            s = fmaf(xv[j].y, av.y, s);
            s = fmaf(xv[j].z, av.z, s);
            s = fmaf(xv[j].w, av.w, s);
        }
        acc[r] = s;
    }
#pragma unroll
    for (int r = 0; r < 16; ++r) {
#pragma unroll
        for (int off = 1; off < 64; off <<= 1)
            acc[r] += __shfl_xor(acc[r], off);
    }
    __shared__ float red[4][16];
    int lane = t & 63, w = t >> 6;
    if (lane < 16) red[w][lane] = acc[lane];
    __syncthreads();
    if (t < 16)
        xr[4096 + t] = (_Float16)(red[0][t] + red[1][t] + red[2][t] + red[3][t]);
    else if (t < 64)
        xr[4112 + (t - 16)] = (_Float16)0.f;
}

// ---------------------------------------------------------------------------
// P2: W dequant + lora/zero pad cols, one launch.
// bid < 4096: one thread per 16-weight group. bid >= 4096: pad cols 4096..4159.
// ---------------------------------------------------------------------------
__global__ __launch_bounds__(256) void w_dequant2(const int* __restrict__ qw,
                                                  const float* __restrict__ sc,
                                                  const float* __restrict__ lb,
                                                  const float* __restrict__ alphap,
                                                  _Float16* __restrict__ Wh) {
    int bid = blockIdx.x;
    int t = threadIdx.x;
    if (bid < 4096) {
        int grp = bid * 256 + t;                   // 0..1048575
        int o = grp >> 8;
        int i0 = (grp & 255) << 4;
        const int* qp = qw + (size_t)grp * 8;
        iv4 q0 = *(const iv4*)qp;
        iv4 q1 = *(const iv4*)(qp + 4);
        float s = sc[grp];
        _Float16 c0h = (_Float16)(s * (2.0f / 15.0f));
        _Float16 c1h = (_Float16)(-s);
        h2 c0 = {c0h, c0h}, c1 = {c1h, c1h};
        h2 m1024 = {(_Float16)-1024.f, (_Float16)-1024.f};
        union { h2 h[4]; iv4 v; } o0, o1;
        int vals[8] = {q0.x, q0.y, q0.z, q0.w, q1.x, q1.y, q1.z, q1.w};
#pragma unroll
        for (int e = 0; e < 8; ++e) {
            unsigned wv = (unsigned)vals[e];
            unsigned qb = (wv & 15u) | ((wv & 0xF0u) << 12) | 0x64006400u;
            h2 qh;
            __builtin_memcpy(&qh, &qb, 4);
            h2 r = (qh + m1024) * c0 + c1;
            if (e < 4) o0.h[e] = r; else o1.h[e - 4] = r;
        }
        _Float16* wp = Wh + (size_t)o * KE + i0;
        *(iv4*)(wp) = o0.v;
        *(iv4*)(wp + 8) = o1.v;
    } else {
        int c = (bid - 4096) * 256 + t;            // 0..32767
        int o = c >> 3, jj = c & 7;                // 8 chunks x 8 f16 = 64 cols
        union { p2 h[4]; iv4 v; } u;
        u.v = iv4{0, 0, 0, 0};
        if (jj < 2) {
            float al = alphap[0];
            const float* wp = lb + (size_t)o * 16 + jj * 8;
#pragma unroll
            for (int e = 0; e < 4; ++e)
                u.h[e] = __builtin_amdgcn_cvt_pkrtz(al * wp[2 * e], al * wp[2 * e + 1]);
        }
        *(iv4*)(Wh + (size_t)o * KE + 4096 + jj * 8) = u.v;
    }
}

// ---------------------------------------------------------------------------
// Pass-2 GEMM v3: out = xh[1024][KE] @ Wh[4096][KE]^T, f32 accum.
// 256 blocks x 512 thr (8 waves: wm,wn,kg = 2x2x2; wave tile 64x64, kg halves
// each K-step). BM=BN=128, BK=128, 32 main steps + one 64-wide tail step.
// LDS 128KB: A f16 dbuf [128 rows][256B] @0 (32KB/buf), B dbuf @65536.
// Swizzle: DMA dest linear; SOURCE granule pre-XOR (p ^ row&15); ds_read XOR.
// Dist-1 DMA prefetch, vmcnt(0)+raw s_barrier once per BK=128 (half the
// barrier/drain count of R8's BK=64).
// XCD map: each XCD owns 8by x 4bx -> its B strip (4.3MB) ~L2-resident.
// ---------------------------------------------------------------------------
__global__ __launch_bounds__(512, 1) void qlora_gemm2(
        const _Float16* __restrict__ xh, const _Float16* __restrict__ Wh,
        float* __restrict__ out)
{
    __shared__ __align__(16) char lds[131072];

    int bid = blockIdx.x;
    int xcd = bid & 7, j = bid >> 3;    // j 0..31
    int by = j & 7, bx = xcd * 4 + (j >> 3);
    int bm0 = by << 7, bn0 = bx << 7;

    int t = threadIdx.x;
    int lane = t & 63;
    int wid = t >> 6;                   // 0..7
    int kg = wid & 1, wn = (wid >> 1) & 1, wm = wid >> 2;
    int rl = lane & 15, hq = lane >> 4;

    // ---- main staging map: inst i covers row i*32 + (t>>4), slot p = t&15 ----
    int sr = t >> 4;                    // 0..31
    int sp = t & 15;
    int sg = sp ^ (sr & 15);            // pre-swizzled source granule
    const char* asrc[4];
    const char* bsrc[4];
#pragma unroll
    for (int i = 0; i < 4; ++i) {
        asrc[i] = (const char*)(xh + (size_t)(bm0 + i * 32 + sr) * KE) + sg * 16;
        bsrc[i] = (const char*)(Wh + (size_t)(bn0 + i * 32 + sr) * KE) + sg * 16;
    }
    // ---- tail staging map (64-col step): row i*64 + (t>>3), p = t&7 ----
    int tr = t >> 3;                    // 0..63
    int tg = (t & 7) ^ (tr & 7);
    const char* atail[2];
    const char* btail[2];
#pragma unroll
    for (int i = 0; i < 2; ++i) {
        atail[i] = (const char*)(xh + (size_t)(bm0 + i * 64 + tr) * KE + 4096) + tg * 16;
        btail[i] = (const char*)(Wh + (size_t)(bn0 + i * 64 + tr) * KE + 4096) + tg * 16;
    }

    auto GLOAD = [&](int ts, int buf) {
        char* Ad = lds + buf * 32768;
        char* Bd = lds + 65536 + buf * 32768;
        size_t off = (size_t)ts * 256;
#pragma unroll
        for (int i = 0; i < 4; ++i) {
            __builtin_amdgcn_global_load_lds(
                (const __attribute__((address_space(1))) u32*)(asrc[i] + off),
                (__attribute__((address_space(3))) u32*)(Ad + i * 8192 + t * 16), 16, 0, 0);
            __builtin_amdgcn_global_load_lds(
                (const __attribute__((address_space(1))) u32*)(bsrc[i] + off),
                (__attribute__((address_space(3))) u32*)(Bd + i * 8192 + t * 16), 16, 0, 0);
        }
    };
    auto GLOAD_TAIL = [&](int buf) {
        char* Ad = lds + buf * 32768;
        char* Bd = lds + 65536 + buf * 32768;
#pragma unroll
        for (int i = 0; i < 2; ++i) {
            __builtin_amdgcn_global_load_lds(
                (const __attribute__((address_space(1))) u32*)(atail[i]),
                (__attribute__((address_space(3))) u32*)(Ad + i * 8192 + t * 16), 16, 0, 0);
            __builtin_amdgcn_global_load_lds(
                (const __attribute__((address_space(1))) u32*)(btail[i]),
                (__attribute__((address_space(3))) u32*)(Bd + i * 8192 + t * 16), 16, 0, 0);
        }
    };

    fv4 acc[4][4];
#pragma unroll
    for (int m = 0; m < 4; ++m)
#pragma unroll
        for (int n = 0; n < 4; ++n)
            acc[m][n] = fv4{0.f, 0.f, 0.f, 0.f};

    auto COMPUTE = [&](int buf) {
        const char* As = lds + buf * 32768;
        const char* Bs = lds + 65536 + buf * 32768;
#pragma unroll
        for (int s = 0; s < 2; ++s) {
            f16x8 a[4], b[4];
            int gk = kg * 8 + s * 4 + hq;           // granule 0..15
            int gs = (gk ^ rl) << 4;                // XOR row&15 (= rl)
#pragma unroll
            for (int m = 0; m < 4; ++m)
                a[m] = *(const f16x8*)(As + (wm * 64 + m * 16 + rl) * 256 + gs);
#pragma unroll
            for (int n = 0; n < 4; ++n)
                b[n] = *(const f16x8*)(Bs + (wn * 64 + n * 16 + rl) * 256 + gs);
            __builtin_amdgcn_s_setprio(1);
#pragma unroll
            for (int m = 0; m < 4; ++m)
#pragma unroll
                for (int n = 0; n < 4; ++n)
                    acc[m][n] = __builtin_amdgcn_mfma_f32_16x16x32_f16(
                        a[m], b[n], acc[m][n], 0, 0, 0);
            __builtin_amdgcn_s_setprio(0);
        }
    };
    auto COMPUTE_TAIL = [&](int buf) {
        const char* As = lds + buf * 32768;
        const char* Bs = lds + 65536 + buf * 32768;
        f16x8 a[4], b[4];
        int gk = kg * 4 + hq;                       // granule 0..7 (128B rows)
        int gs = (gk ^ (rl & 7)) << 4;
#pragma unroll
        for (int m = 0; m < 4; ++m)
            a[m] = *(const f16x8*)(As + (wm * 64 + m * 16 + rl) * 128 + gs);
#pragma unroll
        for (int n = 0; n < 4; ++n)
            b[n] = *(const f16x8*)(Bs + (wn * 64 + n * 16 + rl) * 128 + gs);
        __builtin_amdgcn_s_setprio(1);
#pragma unroll
        for (int m = 0; m < 4; ++m)
#pragma unroll
            for (int n = 0; n < 4; ++n)
                acc[m][n] = __builtin_amdgcn_mfma_f32_16x16x32_f16(
                    a[m], b[n], acc[m][n], 0, 0, 0);
        __builtin_amdgcn_s_setprio(0);
    };

    // ---- prologue ----
    GLOAD(0, 0);
    asm volatile("s_waitcnt vmcnt(0)" ::: "memory");
    __builtin_amdgcn_s_barrier();
    __builtin_amdgcn_sched_barrier(0);

    // ---- main loop: 32 x BK=128, dist-1 prefetch ----
#pragma unroll 1
    for (int ts = 0; ts < 32; ++ts) {
        if (ts < 31) GLOAD(ts + 1, (ts + 1) & 1);
        else         GLOAD_TAIL(0);                // tail lands in buf0
        COMPUTE(ts & 1);
        asm volatile("s_waitcnt vmcnt(0) lgkmcnt(0)" ::: "memory");
        __builtin_amdgcn_s_barrier();
        __builtin_amdgcn_sched_barrier(0);
    }
    COMPUTE_TAIL(0);

    // ---- kg-split reduction + store ----
    __syncthreads();
    if (kg == 1) {
        char* dmp = lds + (wm * 2 + wn) * 16384;
#pragma unroll
        for (int m = 0; m < 4; ++m)
#pragma unroll
            for (int n = 0; n < 4; ++n)
                *(fv4*)(dmp + (m * 4 + n) * 1024 + lane * 16) = acc[m][n];
    }
    __syncthreads();
    if (kg == 0) {
        const char* dmp = lds + (wm * 2 + wn) * 16384;
#pragma unroll
        for (int m = 0; m < 4; ++m) {
            int row0 = bm0 + wm * 64 + m * 16 + hq * 4;
#pragma unroll
            for (int n = 0; n < 4; ++n) {
                fv4 p = *(const fv4*)(dmp + (m * 4 + n) * 1024 + lane * 16);
                fv4 v = acc[m][n];
                v.x += p.x; v.y += p.y; v.z += p.z; v.w += p.w;
                int col = bn0 + wn * 64 + n * 16 + rl;
#pragma unroll
                for (int r = 0; r < 4; ++r)
                    out[(size_t)(row0 + r) * N_OUT + col] = v[r];
            }
        }
    }
}

extern "C" void kernel_launch(void* const* d_in, const int* in_sizes, int n_in,
                              void* d_out, int out_size, void* d_ws, size_t ws_size,
                              hipStream_t stream) {
    const float* x  = (const float*)d_in[0];
    const int*   qw = (const int*)d_in[1];
    const float* sc = (const float*)d_in[2];
    const float* la = (const float*)d_in[3];
    const float* lb = (const float*)d_in[4];
    const float* al = (const float*)d_in[5];
    float* out = (float*)d_out;

    const size_t WH_BYTES = (size_t)N_OUT * KE * 2;   // 34,078,720
    _Float16* Wh = (_Float16*)d_ws;
    _Float16* xh = (_Float16*)((char*)d_ws + WH_BYTES);
    (void)ws_size; (void)n_in; (void)in_sizes; (void)out_size;

    x_prep<<<1024, 256, 0, stream>>>(x, la, xh);
    w_dequant2<<<4224, 256, 0, stream>>>(qw, sc, lb, al, Wh);
    qlora_gemm2<<<256, 512, 0, stream>>>(xh, Wh, out);
}

// Round 10
// 69.751 us; speedup vs baseline: 2.0612x; 1.0484x over previous
//
#include <hip/hip_runtime.h>

typedef __attribute__((ext_vector_type(2))) _Float16 h2;
typedef __attribute__((ext_vector_type(2))) __fp16 p2;   // cvt_pkrtz return type
typedef __attribute__((ext_vector_type(8))) _Float16 f16x8;
typedef __attribute__((ext_vector_type(4))) float fv4;
typedef __attribute__((ext_vector_type(4))) int iv4;
typedef __attribute__((ext_vector_type(2))) int iv2;
typedef unsigned int u32;

#define K_IN 4096
#define N_OUT 4096
#define KE 4160   /* 4096 data + 16 lora + 48 zero pad; 65 x BK=64 exactly */

// ---------------------------------------------------------------------------
// Fused prep (one launch):
//   bid <  1024          : x_prep  (xa dots + xh row build), b = bid
//   1024 <= bid < 5120   : w_dequant, grp block = bid-1024
//   5120 <= bid < 5248   : W pad cols 4096..4159
// ---------------------------------------------------------------------------
__global__ __launch_bounds__(256) void prep_all(
        const float* __restrict__ x, const float* __restrict__ la,
        const int* __restrict__ qw, const float* __restrict__ sc,
        const float* __restrict__ lb, const float* __restrict__ alphap,
        _Float16* __restrict__ xh, _Float16* __restrict__ Wh)
{
    int bid = blockIdx.x;
    int t = threadIdx.x;
    if (bid < 1024) {
        int b = bid;
        const fv4* xp = (const fv4*)(x + (size_t)b * K_IN);
        _Float16* xr = xh + (size_t)b * KE;
        fv4 xv[4];
#pragma unroll
        for (int j = 0; j < 4; ++j) xv[j] = xp[t + j * 256];
#pragma unroll
        for (int j = 0; j < 4; ++j) {
            union { p2 h[2]; iv2 v; } u;
            u.h[0] = __builtin_amdgcn_cvt_pkrtz(xv[j].x, xv[j].y);
            u.h[1] = __builtin_amdgcn_cvt_pkrtz(xv[j].z, xv[j].w);
            *(iv2*)(xr + (size_t)(t + j * 256) * 4) = u.v;
        }
        float acc[16];
#pragma unroll
        for (int r = 0; r < 16; ++r) {
            const fv4* ap = (const fv4*)(la + (size_t)r * K_IN);
            float s = 0.f;
#pragma unroll
            for (int j = 0; j < 4; ++j) {
                fv4 av = ap[t + j * 256];
                s = fmaf(xv[j].x, av.x, s);
                s = fmaf(xv[j].y, av.y, s);
                s = fmaf(xv[j].z, av.z, s);
                s = fmaf(xv[j].w, av.w, s);
            }
            acc[r] = s;
        }
#pragma unroll
        for (int r = 0; r < 16; ++r) {
#pragma unroll
            for (int off = 1; off < 64; off <<= 1)
                acc[r] += __shfl_xor(acc[r], off);
        }
        __shared__ float red[4][16];
        int lane = t & 63, w = t >> 6;
        if (lane < 16) red[w][lane] = acc[lane];
        __syncthreads();
        if (t < 16)
            xr[4096 + t] = (_Float16)(red[0][t] + red[1][t] + red[2][t] + red[3][t]);
        else if (t < 64)
            xr[4112 + (t - 16)] = (_Float16)0.f;
    } else if (bid < 5120) {
        int grp = (bid - 1024) * 256 + t;          // 0..1048575
        int o = grp >> 8;
        int i0 = (grp & 255) << 4;
        const int* qp = qw + (size_t)grp * 8;
        iv4 q0 = *(const iv4*)qp;
        iv4 q1 = *(const iv4*)(qp + 4);
        float s = sc[grp];
        _Float16 c0h = (_Float16)(s * (2.0f / 15.0f));
        _Float16 c1h = (_Float16)(-s);
        h2 c0 = {c0h, c0h}, c1 = {c1h, c1h};
        h2 m1024 = {(_Float16)-1024.f, (_Float16)-1024.f};
        union { h2 h[4]; iv4 v; } o0, o1;
        int vals[8] = {q0.x, q0.y, q0.z, q0.w, q1.x, q1.y, q1.z, q1.w};
#pragma unroll
        for (int e = 0; e < 8; ++e) {
            unsigned wv = (unsigned)vals[e];
            unsigned qb = (wv & 15u) | ((wv & 0xF0u) << 12) | 0x64006400u;
            h2 qh;
            __builtin_memcpy(&qh, &qb, 4);
            h2 r = (qh + m1024) * c0 + c1;
            if (e < 4) o0.h[e] = r; else o1.h[e - 4] = r;
        }
        _Float16* wp = Wh + (size_t)o * KE + i0;
        *(iv4*)(wp) = o0.v;
        *(iv4*)(wp + 8) = o1.v;
    } else {
        int c = (bid - 5120) * 256 + t;            // 0..32767
        int o = c >> 3, jj = c & 7;
        union { p2 h[4]; iv4 v; } u;
        u.v = iv4{0, 0, 0, 0};
        if (jj < 2) {
            float al = alphap[0];
            const float* wp = lb + (size_t)o * 16 + jj * 8;
#pragma unroll
            for (int e = 0; e < 4; ++e)
                u.h[e] = __builtin_amdgcn_cvt_pkrtz(al * wp[2 * e], al * wp[2 * e + 1]);
        }
        *(iv4*)(Wh + (size_t)o * KE + 4096 + jj * 8) = u.v;
    }
}

// ---------------------------------------------------------------------------
// GEMM: out = xh[1024][KE] @ Wh[4096][KE]^T, f32 accum.
// 256 blocks x 512 thr (8 waves: wm,wn,kg = 2x2x2; wave 64x64 over its k32
// half). BM=BN=128, BK=64, 65 steps (KE = 65*64 exactly, no tail).
// LDS 96KB: 3 bufs x (A 16KB + B 16KB); dist-2 DMA prefetch; per step
// COUNTED s_waitcnt vmcnt(4) -- next tile's 4 loads already landed, the
// tile-after's 4 stay in flight. Never drains to 0 in-loop.
// Swizzle: DMA dest linear; source granule pre-XOR (p ^ row&7); XOR ds_read.
// XCD map: each XCD owns 8by x 4bx -> B strip (4.3MB) L2-resident.
// ---------------------------------------------------------------------------
__global__ __launch_bounds__(512, 1) void qlora_gemm2(
        const _Float16* __restrict__ xh, const _Float16* __restrict__ Wh,
        float* __restrict__ out)
{
    __shared__ __align__(16) char lds[98304];

    int bid = blockIdx.x;
    int xcd = bid & 7, j = bid >> 3;    // j 0..31
    int by = j & 7, bx = xcd * 4 + (j >> 3);
    int bm0 = by << 7, bn0 = bx << 7;

    int t = threadIdx.x;
    int lane = t & 63;
    int wid = t >> 6;                   // 0..7
    int kg = wid & 1, wn = (wid >> 1) & 1, wm = wid >> 2;
    int rl = lane & 15, hq = lane >> 4;

    // staging map: instr i in {0,1}: row = i*64 + (t>>3), slot p = t&7
    int sr = t >> 3;                    // 0..63
    int sp = t & 7;
    int sg = sp ^ (sr & 7);             // pre-swizzled source granule
    const char* asrc[2];
    const char* bsrc[2];
#pragma unroll
    for (int i = 0; i < 2; ++i) {
        asrc[i] = (const char*)(xh + (size_t)(bm0 + i * 64 + sr) * KE) + sg * 16;
        bsrc[i] = (const char*)(Wh + (size_t)(bn0 + i * 64 + sr) * KE) + sg * 16;
    }

    auto GLOAD = [&](int ts, int buf) {
        char* Ad = lds + buf * 32768;
        char* Bd = lds + buf * 32768 + 16384;
        size_t off = (size_t)ts * 128;
#pragma unroll
        for (int i = 0; i < 2; ++i) {
            __builtin_amdgcn_global_load_lds(
                (const __attribute__((address_space(1))) u32*)(asrc[i] + off),
                (__attribute__((address_space(3))) u32*)(Ad + i * 8192 + t * 16), 16, 0, 0);
            __builtin_amdgcn_global_load_lds(
                (const __attribute__((address_space(1))) u32*)(bsrc[i] + off),
                (__attribute__((address_space(3))) u32*)(Bd + i * 8192 + t * 16), 16, 0, 0);
        }
    };

    fv4 acc[4][4];
#pragma unroll
    for (int m = 0; m < 4; ++m)
#pragma unroll
        for (int n = 0; n < 4; ++n)
            acc[m][n] = fv4{0.f, 0.f, 0.f, 0.f};

    auto COMPUTE = [&](int buf) {
        const char* As = lds + buf * 32768;
        const char* Bs = lds + buf * 32768 + 16384;
        f16x8 a[4], b[4];
        int gk = kg * 4 + hq;                   // granule 0..7 (this wave's k32)
        int gs = (gk ^ (rl & 7)) << 4;
#pragma unroll
        for (int m = 0; m < 4; ++m)
            a[m] = *(const f16x8*)(As + (wm * 64 + m * 16 + rl) * 128 + gs);
#pragma unroll
        for (int n = 0; n < 4; ++n)
            b[n] = *(const f16x8*)(Bs + (wn * 64 + n * 16 + rl) * 128 + gs);
        __builtin_amdgcn_s_setprio(1);
#pragma unroll
        for (int m = 0; m < 4; ++m)
#pragma unroll
            for (int n = 0; n < 4; ++n)
                acc[m][n] = __builtin_amdgcn_mfma_f32_16x16x32_f16(
                    a[m], b[n], acc[m][n], 0, 0, 0);
        __builtin_amdgcn_s_setprio(0);
    };

    // ---- prologue: tiles 0,1 in flight; wait tile0 only (counted) ----
    GLOAD(0, 0);
    GLOAD(1, 1);
    asm volatile("s_waitcnt vmcnt(4)" ::: "memory");
    __builtin_amdgcn_s_barrier();
    __builtin_amdgcn_sched_barrier(0);

    // ---- main loop: 65 steps, dist-2 prefetch, counted vmcnt ----
#pragma unroll 1
    for (int ts = 0; ts < 65; ++ts) {
        if (ts <= 62) GLOAD(ts + 2, (ts + 2) % 3);
        COMPUTE(ts % 3);
        if (ts <= 62) {
            asm volatile("s_waitcnt vmcnt(4)" ::: "memory");  // tile ts+1 landed
            __builtin_amdgcn_s_barrier();
            __builtin_amdgcn_sched_barrier(0);
        } else if (ts == 63) {
            asm volatile("s_waitcnt vmcnt(0)" ::: "memory");  // tile 64 landed
            __builtin_amdgcn_s_barrier();
            __builtin_amdgcn_sched_barrier(0);
        }
    }

    // ---- kg-split reduction + store ----
    __syncthreads();
    if (kg == 1) {
        char* dmp = lds + (wm * 2 + wn) * 16384;
#pragma unroll
        for (int m = 0; m < 4; ++m)
#pragma unroll
            for (int n = 0; n < 4; ++n)
                *(fv4*)(dmp + (m * 4 + n) * 1024 + lane * 16) = acc[m][n];
    }
    __syncthreads();
    if (kg == 0) {
        const char* dmp = lds + (wm * 2 + wn) * 16384;
#pragma unroll
        for (int m = 0; m < 4; ++m) {
            int row0 = bm0 + wm * 64 + m * 16 + hq * 4;
#pragma unroll
            for (int n = 0; n < 4; ++n) {
                fv4 p = *(const fv4*)(dmp + (m * 4 + n) * 1024 + lane * 16);
                fv4 v = acc[m][n];
                v.x += p.x; v.y += p.y; v.z += p.z; v.w += p.w;
                int col = bn0 + wn * 64 + n * 16 + rl;
#pragma unroll
                for (int r = 0; r < 4; ++r)
                    out[(size_t)(row0 + r) * N_OUT + col] = v[r];
            }
        }
    }
}

extern "C" void kernel_launch(void* const* d_in, const int* in_sizes, int n_in,
                              void* d_out, int out_size, void* d_ws, size_t ws_size,
                              hipStream_t stream) {
    const float* x  = (const float*)d_in[0];
    const int*   qw = (const int*)d_in[1];
    const float* sc = (const float*)d_in[2];
    const float* la = (const float*)d_in[3];
    const float* lb = (const float*)d_in[4];
    const float* al = (const float*)d_in[5];
    float* out = (float*)d_out;

    const size_t WH_BYTES = (size_t)N_OUT * KE * 2;   // 34,078,720
    _Float16* Wh = (_Float16*)d_ws;
    _Float16* xh = (_Float16*)((char*)d_ws + WH_BYTES);
    (void)ws_size; (void)n_in; (void)in_sizes; (void)out_size;

    prep_all<<<5248, 256, 0, stream>>>(x, la, qw, sc, lb, al, xh, Wh);
    qlora_gemm2<<<256, 512, 0, stream>>>(xh, Wh, out);
}